// Round 11
// baseline (322.202 us; speedup 1.0000x reference)
//
#include <hip/hip_runtime.h>
#include <hip/hip_bf16.h>
#include <math.h>

typedef short bf16x8 __attribute__((ext_vector_type(8)));
typedef float f32x4 __attribute__((ext_vector_type(4)));

#define DEG_CAP 128   // per-node LDS logit cache; fallback path beyond
#define EPB 8192      // edges per fat partition block

// ---- bf16 helpers (RN-even down-convert, exact up-convert) ----
__device__ __forceinline__ unsigned short f2bf(float f) {
    unsigned x = __float_as_uint(f);
    unsigned r = x + 0x7FFFu + ((x >> 16) & 1u);
    return (unsigned short)(r >> 16);
}
__device__ __forceinline__ float bf2f(unsigned short u) {
    return __uint_as_float(((unsigned)u) << 16);
}

// ===================== prep: bucket-count + conv_x + Wt + Q =====================
__global__ __launch_bounds__(256) void prep(const float* __restrict__ x,
                                            unsigned short* __restrict__ X16, int nx4,
                                            const int* __restrict__ dst, int E, int Etot,
                                            int* __restrict__ bcnt,
                                            const float* __restrict__ W1,
                                            unsigned short* __restrict__ Wt1,
                                            const float* __restrict__ W2,
                                            unsigned short* __restrict__ Wt2,
                                            const float* __restrict__ as1,
                                            const float* __restrict__ ad1,
                                            float* __restrict__ Q1,
                                            const float* __restrict__ as2,
                                            const float* __restrict__ ad2,
                                            float* __restrict__ Q2,
                                            int nb_bucket, int nb_convx) {
    int b = blockIdx.x, t = threadIdx.x;
    if (b < nb_bucket) {                      // ---- bucket histogram (dst>>8) ----
        __shared__ int h[256];
        h[t] = 0;
        __syncthreads();
        int k0 = b * EPB;
        for (int i = t; i < EPB; i += 256) {
            int k = k0 + i;
            if (k < Etot) {
                int d = k < E ? dst[k] : k - E;
                atomicAdd(&h[d >> 8], 1);
            }
        }
        __syncthreads();
        if (h[t]) atomicAdd(bcnt + t, h[t]);
        return;
    }
    b -= nb_bucket;
    if (b < nb_convx) {                       // ---- x fp32 -> bf16 (float4) ----
        int i = b * 256 + t;
        if (i < nx4) {
            float4 v = ((const float4*)x)[i];
            ushort4 u;
            u.x = f2bf(v.x); u.y = f2bf(v.y); u.z = f2bf(v.z); u.w = f2bf(v.w);
            ((ushort4*)X16)[i] = u;
        }
        return;
    }
    b -= nb_convx;
    if (b < 128) {                            // ---- W1 [128][256] -> Wt1 [256][128]
        int id = b * 256 + t;
        int k = id >> 8, m = id & 255;
        Wt1[m * 128 + k] = f2bf(W1[id]);
        return;
    }
    b -= 128;
    if (b < 128) {                            // ---- W2 [256][128] -> Wt2 [128][256]
        int id = b * 256 + t;
        int k = id >> 7, m = id & 127;
        Wt2[m * 256 + k] = f2bf(W2[id]);
        return;
    }
    b -= 128;
    int wave = t >> 6, lane = t & 63;
    if (b < 32) {                             // ---- Q1 [128][8] ----
        int k = b * 4 + wave;
        if (k < 128) {
            float p[8];
            #pragma unroll
            for (int h = 0; h < 4; ++h) {
                float w = W1[k * 256 + h * 64 + lane];
                p[h] = w * as1[h * 64 + lane];
                p[4 + h] = w * ad1[h * 64 + lane];
            }
            #pragma unroll
            for (int j = 0; j < 8; ++j)
                #pragma unroll
                for (int o = 32; o; o >>= 1) p[j] += __shfl_xor(p[j], o);
            if (lane == 0) {
                #pragma unroll
                for (int j = 0; j < 8; ++j) Q1[k * 8 + j] = p[j];
            }
        }
        return;
    }
    b -= 32;
    {                                         // ---- Q2 [256][2] ----
        int k = b * 4 + wave;
        if (k < 256) {
            float w0 = W2[k * 128 + lane], w1 = W2[k * 128 + 64 + lane];
            float s = w0 * as2[lane] + w1 * as2[64 + lane];
            float d = w0 * ad2[lane] + w1 * ad2[64 + lane];
            #pragma unroll
            for (int o = 32; o; o >>= 1) { s += __shfl_xor(s, o); d += __shfl_xor(d, o); }
            if (lane == 0) { Q2[k * 2] = s; Q2[k * 2 + 1] = d; }
        }
    }
}

// ===================== bucket scan (1 block, <=256 buckets) =====================
__global__ __launch_bounds__(256) void bscan(const int* __restrict__ bcnt,
                                             int* __restrict__ bbase,
                                             int* __restrict__ bcursor,
                                             int* __restrict__ rowptr,
                                             int nbuck, int N, int Etot) {
    __shared__ int s[256];
    int t = threadIdx.x;
    int v = t < nbuck ? bcnt[t] : 0;
    s[t] = v;
    __syncthreads();
    #pragma unroll
    for (int o = 1; o < 256; o <<= 1) {
        int add = t >= o ? s[t - o] : 0;
        __syncthreads();
        s[t] += add;
        __syncthreads();
    }
    int excl = s[t] - v;
    if (t < nbuck) { bbase[t] = excl; bcursor[t] = excl; }
    if (t == 0) rowptr[N] = Etot;
}

// ===================== fused: partition + attn1 (X.Q1) =====================
__global__ __launch_bounds__(256) void part_attn1(const unsigned short* __restrict__ Xb,
                                                  const float* __restrict__ Q,
                                                  float* __restrict__ es,
                                                  float* __restrict__ ed,
                                                  int N, int PB,
                                                  const int* __restrict__ src,
                                                  const int* __restrict__ dst,
                                                  int E, int Etot,
                                                  int* __restrict__ bcursor,
                                                  int* __restrict__ ebuf) {
    int t = threadIdx.x;
    if ((int)blockIdx.x < PB) {
        __shared__ int h[256], gb[256], lc[256];
        h[t] = 0;
        __syncthreads();
        int k0 = (int)blockIdx.x * EPB;
        for (int i = t; i < EPB; i += 256) {
            int k = k0 + i;
            if (k < Etot) {
                int d = k < E ? dst[k] : k - E;
                atomicAdd(&h[d >> 8], 1);
            }
        }
        __syncthreads();
        if (h[t]) gb[t] = atomicAdd(bcursor + t, h[t]);
        lc[t] = 0;
        __syncthreads();
        for (int i = t; i < EPB; i += 256) {
            int k = k0 + i;
            if (k < Etot) {
                int s = k < E ? src[k] : k - E;
                int d = k < E ? dst[k] : k - E;
                int bkt = d >> 8;
                int p = atomicAdd(&lc[bkt], 1);
                ebuf[gb[bkt] + p] = s | ((d & 0xFF) << 16);  // src:16|dlow:8
            }
        }
        return;
    }
    int wave = t >> 6, lane = t & 63;
    int n = ((int)blockIdx.x - PB) * 4 + wave;
    if (n >= N) return;
    ushort2 xv = *(const ushort2*)(Xb + (size_t)n * 128 + lane * 2);
    float x0 = bf2f(xv.x), x1 = bf2f(xv.y);
    const float* q0 = Q + (size_t)(lane * 2) * 8;
    const float* q1 = q0 + 8;
    float p[8];
    #pragma unroll
    for (int j = 0; j < 8; ++j) p[j] = x0 * q0[j] + x1 * q1[j];
    #pragma unroll
    for (int j = 0; j < 8; ++j)
        #pragma unroll
        for (int o = 32; o; o >>= 1) p[j] += __shfl_xor(p[j], o);
    if (lane == 0) {
        #pragma unroll
        for (int h = 0; h < 4; ++h) {
            es[n * 4 + h] = p[h];
            ed[n * 4 + h] = p[4 + h];
        }
    }
}

// ===================== per-bucket CSR build (XCD-local writes) =================
__global__ __launch_bounds__(256) void bucket_scatter(const int* __restrict__ bbase,
                                                      const int* __restrict__ bcnt,
                                                      const int* __restrict__ ebuf,
                                                      int* __restrict__ rowptr,
                                                      int* __restrict__ col, int N) {
    __shared__ int ldeg[256], loff[256], lcur[256];
    int b = blockIdx.x, t = threadIdx.x;
    int base = bbase[b], cnt = bcnt[b];
    ldeg[t] = 0;
    __syncthreads();
    for (int i = t; i < cnt; i += 256) {
        int e = ebuf[base + i];
        atomicAdd(&ldeg[(e >> 16) & 0xFF], 1);
    }
    __syncthreads();
    int v = ldeg[t];
    loff[t] = v;
    __syncthreads();
    #pragma unroll
    for (int o = 1; o < 256; o <<= 1) {
        int add = t >= o ? loff[t - o] : 0;
        __syncthreads();
        loff[t] += add;
        __syncthreads();
    }
    int excl = loff[t] - v;
    __syncthreads();
    loff[t] = excl;
    lcur[t] = 0;
    int node = b * 256 + t;
    if (node < N) rowptr[node] = base + excl;
    __syncthreads();
    for (int i = t; i < cnt; i += 256) {
        int e = ebuf[base + i];
        int dl = (e >> 16) & 0xFF;
        int p = atomicAdd(&lcur[dl], 1);
        col[base + loff[dl] + p] = e & 0xFFFF;
    }
}

// ===================== agg1_fused: softmax + x-agg (LDS G) + MFMA proj ======
// Block = 16 nodes. Waves 0-3 each aggregate 4 nodes into LDS G rows, then
// the 4 waves run the per-head (wave=head) 16x64 MFMA projection + bias + ELU.
__global__ __launch_bounds__(256) void agg1_fused(const int* __restrict__ rowptr,
                                                  const int* __restrict__ col,
                                                  const unsigned short* __restrict__ x16,
                                                  const float* __restrict__ es,
                                                  const float* __restrict__ ed,
                                                  const unsigned short* __restrict__ Wt1,
                                                  const float* __restrict__ b1,
                                                  unsigned short* __restrict__ B16,
                                                  int N) {
    __shared__ unsigned short Glds[16][520];  // +8 pad: MFMA A-read 2-way only
    __shared__ float pl[4][DEG_CAP * 4];
    __shared__ int ic[4][DEG_CAP];
    __shared__ float zs[4][4];
    int wave = threadIdx.x >> 6, lane = threadIdx.x & 63;
    int h = lane >> 4, l16 = lane & 15;
    float* myp = pl[wave];
    int* myc = ic[wave];
    const unsigned short* xbase = x16 + lane * 2;
    // ---- phase 1: per-wave aggregation of 4 nodes ----
    for (int j = 0; j < 4; ++j) {
        int lr = wave * 4 + j;
        int n = blockIdx.x * 16 + lr;
        if (n >= N) break;
        int beg = rowptr[n], end = rowptr[n + 1], deg = end - beg;
        float edv = ed[n * 4 + h];
        float z = 0.f;
        float a0c0 = 0.f, a0c1 = 0.f, a1c0 = 0.f, a1c1 = 0.f;
        float a2c0 = 0.f, a2c1 = 0.f, a3c0 = 0.f, a3c1 = 0.f;
        float b0c0 = 0.f, b0c1 = 0.f, b1c0 = 0.f, b1c1 = 0.f;
        float b2c0 = 0.f, b2c1 = 0.f, b3c0 = 0.f, b3c1 = 0.f;
        if (deg <= DEG_CAP) {
            // merged gather + exp + denom pass (no max: logits are small)
            for (int i = l16; i < deg; i += 16) {
                int s = col[beg + i];
                if (h == 0) myc[i] = s;
                float e = es[s * 4 + h] + edv;
                e = e > 0.f ? e : 0.2f * e;
                float pp = __expf(e);
                myp[i * 4 + h] = pp;
                z += pp;
            }
            #pragma unroll
            for (int o = 8; o; o >>= 1) z += __shfl_xor(z, o);
            if (l16 == 0) zs[wave][h] = 1.0f / z;
            __threadfence_block();
            float4 zi = *(float4*)zs[wave];
            int i = 0;
            for (; i + 2 <= deg; i += 2) {
                float4 p0 = *(float4*)(myp + i * 4);
                float4 p1 = *(float4*)(myp + i * 4 + 4);
                int s0 = myc[i], s1 = myc[i + 1];
                ushort2 u0 = *(const ushort2*)(xbase + (size_t)s0 * 128);
                ushort2 u1 = *(const ushort2*)(xbase + (size_t)s1 * 128);
                float x00 = bf2f(u0.x), x01 = bf2f(u0.y);
                float x10 = bf2f(u1.x), x11 = bf2f(u1.y);
                float al0 = p0.x * zi.x, al1 = p0.y * zi.y;
                float al2 = p0.z * zi.z, al3 = p0.w * zi.w;
                float bl0 = p1.x * zi.x, bl1 = p1.y * zi.y;
                float bl2 = p1.z * zi.z, bl3 = p1.w * zi.w;
                a0c0 = fmaf(al0, x00, a0c0); a0c1 = fmaf(al0, x01, a0c1);
                a1c0 = fmaf(al1, x00, a1c0); a1c1 = fmaf(al1, x01, a1c1);
                a2c0 = fmaf(al2, x00, a2c0); a2c1 = fmaf(al2, x01, a2c1);
                a3c0 = fmaf(al3, x00, a3c0); a3c1 = fmaf(al3, x01, a3c1);
                b0c0 = fmaf(bl0, x10, b0c0); b0c1 = fmaf(bl0, x11, b0c1);
                b1c0 = fmaf(bl1, x10, b1c0); b1c1 = fmaf(bl1, x11, b1c1);
                b2c0 = fmaf(bl2, x10, b2c0); b2c1 = fmaf(bl2, x11, b2c1);
                b3c0 = fmaf(bl3, x10, b3c0); b3c1 = fmaf(bl3, x11, b3c1);
            }
            if (i < deg) {
                float4 p0 = *(float4*)(myp + i * 4);
                int s0 = myc[i];
                ushort2 u0 = *(const ushort2*)(xbase + (size_t)s0 * 128);
                float x00 = bf2f(u0.x), x01 = bf2f(u0.y);
                float al0 = p0.x * zi.x, al1 = p0.y * zi.y;
                float al2 = p0.z * zi.z, al3 = p0.w * zi.w;
                a0c0 = fmaf(al0, x00, a0c0); a0c1 = fmaf(al0, x01, a0c1);
                a1c0 = fmaf(al1, x00, a1c0); a1c1 = fmaf(al1, x01, a1c1);
                a2c0 = fmaf(al2, x00, a2c0); a2c1 = fmaf(al2, x01, a2c1);
                a3c0 = fmaf(al3, x00, a3c0); a3c1 = fmaf(al3, x01, a3c1);
            }
        } else {
            // fallback: recompute per edge (deg > DEG_CAP, rare)
            float z2 = 0.f;
            for (int e = beg + l16; e < end; e += 16) {
                float ev = es[col[e] * 4 + h] + edv;
                ev = ev > 0.f ? ev : 0.2f * ev;
                z2 += __expf(ev);
            }
            #pragma unroll
            for (int o = 8; o; o >>= 1) z2 += __shfl_xor(z2, o);
            if (l16 == 0) zs[wave][h] = 1.0f / z2;
            __threadfence_block();
            float4 zi = *(float4*)zs[wave];
            float4 ed4 = *(const float4*)(ed + n * 4);
            for (int e = beg; e < end; ++e) {
                int s = col[e];
                float4 es4 = *(const float4*)(es + s * 4);
                float e0 = es4.x + ed4.x; e0 = e0 > 0.f ? e0 : 0.2f * e0;
                float e1 = es4.y + ed4.y; e1 = e1 > 0.f ? e1 : 0.2f * e1;
                float e2 = es4.z + ed4.z; e2 = e2 > 0.f ? e2 : 0.2f * e2;
                float e3 = es4.w + ed4.w; e3 = e3 > 0.f ? e3 : 0.2f * e3;
                float al0 = __expf(e0) * zi.x;
                float al1 = __expf(e1) * zi.y;
                float al2 = __expf(e2) * zi.z;
                float al3 = __expf(e3) * zi.w;
                ushort2 u0 = *(const ushort2*)(xbase + (size_t)s * 128);
                float x00 = bf2f(u0.x), x01 = bf2f(u0.y);
                a0c0 = fmaf(al0, x00, a0c0); a0c1 = fmaf(al0, x01, a0c1);
                a1c0 = fmaf(al1, x00, a1c0); a1c1 = fmaf(al1, x01, a1c1);
                a2c0 = fmaf(al2, x00, a2c0); a2c1 = fmaf(al2, x01, a2c1);
                a3c0 = fmaf(al3, x00, a3c0); a3c1 = fmaf(al3, x01, a3c1);
            }
        }
        // write G row (4 heads x 2 channels per lane) to LDS
        unsigned short* g = &Glds[lr][lane * 2];
        ushort2 o0 = {f2bf(a0c0 + b0c0), f2bf(a0c1 + b0c1)};
        ushort2 o1 = {f2bf(a1c0 + b1c0), f2bf(a1c1 + b1c1)};
        ushort2 o2 = {f2bf(a2c0 + b2c0), f2bf(a2c1 + b2c1)};
        ushort2 o3 = {f2bf(a3c0 + b3c0), f2bf(a3c1 + b3c1)};
        *(ushort2*)(g + 0)   = o0;
        *(ushort2*)(g + 128) = o1;
        *(ushort2*)(g + 256) = o2;
        *(ushort2*)(g + 384) = o3;
    }
    __syncthreads();
    // ---- phase 2: per-head MFMA projection (wave = head) ----
    int l15 = lane & 15, quad = lane >> 4;
    f32x4 acc[4] = {};
    const unsigned short* brow = Wt1 + (size_t)(wave * 64 + l15) * 128 + quad * 8;
    #pragma unroll
    for (int k0 = 0; k0 < 128; k0 += 32) {
        bf16x8 a = *(const bf16x8*)(&Glds[l15][wave * 128 + quad * 8 + k0]);
        #pragma unroll
        for (int nt = 0; nt < 4; ++nt) {
            bf16x8 b = *(const bf16x8*)(brow + (size_t)nt * 16 * 128 + k0);
            acc[nt] = __builtin_amdgcn_mfma_f32_16x16x32_bf16(a, b, acc[nt], 0, 0, 0);
        }
    }
    int m0 = blockIdx.x * 16;
    #pragma unroll
    for (int nt = 0; nt < 4; ++nt) {
        float bias = b1[wave * 64 + nt * 16 + l15];
        #pragma unroll
        for (int r = 0; r < 4; ++r) {
            int row = m0 + quad * 4 + r;
            if (row < N) {
                float v = acc[nt][r] + bias;
                v = v > 0.f ? v : expm1f(v);
                B16[(size_t)row * 256 + wave * 64 + nt * 16 + l15] = f2bf(v);
            }
        }
    }
}

// ===================== gemm_attn2: GEMM2 (B16@Wt2) + attn2 ==================
__global__ __launch_bounds__(256) void gemm_attn2(const unsigned short* __restrict__ Xb,
                                                  const unsigned short* __restrict__ Wt,
                                                  const float* __restrict__ Q,
                                                  unsigned short* __restrict__ H16,
                                                  float* __restrict__ es,
                                                  float* __restrict__ ed,
                                                  int N, int GB) {
    int wave = threadIdx.x >> 6, lane = threadIdx.x & 63;
    if ((int)blockIdx.x < GB) {
        constexpr int K = 256, M = 128;
        constexpr int NS = M / 64;
        int wid = (int)blockIdx.x * 4 + wave;
        int mt = wid / NS, ns = wid % NS;
        int m0 = mt * 16, n0 = ns * 64;
        if (m0 >= N) return;
        int l15 = lane & 15, quad = lane >> 4;
        int ar = m0 + l15; if (ar >= N) ar = N - 1;
        f32x4 acc[4] = {};
        const unsigned short* arow = Xb + (size_t)ar * K + quad * 8;
        const unsigned short* brow = Wt + (size_t)(n0 + l15) * K + quad * 8;
        for (int k0 = 0; k0 < K; k0 += 32) {
            bf16x8 a = *(const bf16x8*)(arow + k0);
            #pragma unroll
            for (int nt = 0; nt < 4; ++nt) {
                bf16x8 b = *(const bf16x8*)(brow + (size_t)nt * 16 * K + k0);
                acc[nt] = __builtin_amdgcn_mfma_f32_16x16x32_bf16(a, b, acc[nt], 0, 0, 0);
            }
        }
        #pragma unroll
        for (int nt = 0; nt < 4; ++nt)
            #pragma unroll
            for (int r = 0; r < 4; ++r) {
                int row = m0 + quad * 4 + r;
                if (row < N)
                    H16[(size_t)row * M + n0 + nt * 16 + l15] = f2bf(acc[nt][r]);
            }
    } else {
        int n = ((int)blockIdx.x - GB) * 4 + wave;
        if (n >= N) return;
        ushort4 xv = *(const ushort4*)(Xb + (size_t)n * 256 + lane * 4);
        float xr[4] = {bf2f(xv.x), bf2f(xv.y), bf2f(xv.z), bf2f(xv.w)};
        float p0 = 0.f, p1 = 0.f;
        #pragma unroll
        for (int tt = 0; tt < 4; ++tt) {
            float2 q = *(const float2*)(Q + (size_t)(lane * 4 + tt) * 2);
            p0 = fmaf(xr[tt], q.x, p0);
            p1 = fmaf(xr[tt], q.y, p1);
        }
        #pragma unroll
        for (int o = 32; o; o >>= 1) { p0 += __shfl_xor(p0, o); p1 += __shfl_xor(p1, o); }
        if (lane == 0) { es[n] = p0; ed[n] = p1; }
    }
}

// ===================== agg_l2 (no-max softmax; gather h2 rows 256B) =========
__global__ __launch_bounds__(256) void agg_l2(const int* __restrict__ rowptr,
                                              const int* __restrict__ col,
                                              const unsigned short* __restrict__ h16,
                                              const float* __restrict__ es,
                                              const float* __restrict__ ed,
                                              const float* __restrict__ b2,
                                              float* __restrict__ out, int N) {
    __shared__ float pl[4][DEG_CAP];
    __shared__ int ic[4][DEG_CAP];
    int wave = threadIdx.x >> 6, lane = threadIdx.x & 63;
    int n = blockIdx.x * 4 + wave;
    if (n >= N) return;
    int beg = rowptr[n], end = rowptr[n + 1], deg = end - beg;
    float edv = ed[n];
    float* myp = pl[wave];
    int* myc = ic[wave];
    float z = 0.f, zinv;
    int half = lane >> 5, l32 = lane & 31;
    float4 acc0 = make_float4(0.f, 0.f, 0.f, 0.f);
    float4 acc1 = make_float4(0.f, 0.f, 0.f, 0.f);
    float4 acc2 = make_float4(0.f, 0.f, 0.f, 0.f);
    float4 acc3 = make_float4(0.f, 0.f, 0.f, 0.f);
    if (deg <= DEG_CAP) {
        for (int i = lane; i < deg; i += 64) {
            int s = col[beg + i];
            myc[i] = s;
            float e = es[s] + edv;
            e = e > 0.f ? e : 0.2f * e;
            float pp = __expf(e);
            myp[i] = pp;
            z += pp;
        }
        #pragma unroll
        for (int o = 32; o; o >>= 1) z += __shfl_xor(z, o);
        zinv = 1.0f / z;
        __threadfence_block();
        int i = 0;
        for (; i + 8 <= deg; i += 8) {
            int ii0 = i + half, ii1 = i + 2 + half, ii2 = i + 4 + half, ii3 = i + 6 + half;
            float a0 = myp[ii0] * zinv, a1 = myp[ii1] * zinv;
            float a2 = myp[ii2] * zinv, a3 = myp[ii3] * zinv;
            ushort4 u0 = *(const ushort4*)(h16 + (size_t)myc[ii0] * 128 + l32 * 4);
            ushort4 u1 = *(const ushort4*)(h16 + (size_t)myc[ii1] * 128 + l32 * 4);
            ushort4 u2 = *(const ushort4*)(h16 + (size_t)myc[ii2] * 128 + l32 * 4);
            ushort4 u3 = *(const ushort4*)(h16 + (size_t)myc[ii3] * 128 + l32 * 4);
            acc0.x = fmaf(a0, bf2f(u0.x), acc0.x);
            acc0.y = fmaf(a0, bf2f(u0.y), acc0.y);
            acc0.z = fmaf(a0, bf2f(u0.z), acc0.z);
            acc0.w = fmaf(a0, bf2f(u0.w), acc0.w);
            acc1.x = fmaf(a1, bf2f(u1.x), acc1.x);
            acc1.y = fmaf(a1, bf2f(u1.y), acc1.y);
            acc1.z = fmaf(a1, bf2f(u1.z), acc1.z);
            acc1.w = fmaf(a1, bf2f(u1.w), acc1.w);
            acc2.x = fmaf(a2, bf2f(u2.x), acc2.x);
            acc2.y = fmaf(a2, bf2f(u2.y), acc2.y);
            acc2.z = fmaf(a2, bf2f(u2.z), acc2.z);
            acc2.w = fmaf(a2, bf2f(u2.w), acc2.w);
            acc3.x = fmaf(a3, bf2f(u3.x), acc3.x);
            acc3.y = fmaf(a3, bf2f(u3.y), acc3.y);
            acc3.z = fmaf(a3, bf2f(u3.z), acc3.z);
            acc3.w = fmaf(a3, bf2f(u3.w), acc3.w);
        }
        for (; i < deg; i += 2) {
            int ii = i + half;
            if (ii < deg) {
                float a0 = myp[ii] * zinv;
                ushort4 u0 = *(const ushort4*)(h16 + (size_t)myc[ii] * 128 + l32 * 4);
                acc0.x = fmaf(a0, bf2f(u0.x), acc0.x);
                acc0.y = fmaf(a0, bf2f(u0.y), acc0.y);
                acc0.z = fmaf(a0, bf2f(u0.z), acc0.z);
                acc0.w = fmaf(a0, bf2f(u0.w), acc0.w);
            }
        }
    } else {
        for (int e = beg + lane; e < end; e += 64) {
            float ev = es[col[e]] + edv;
            ev = ev > 0.f ? ev : 0.2f * ev;
            z += __expf(ev);
        }
        #pragma unroll
        for (int o = 32; o; o >>= 1) z += __shfl_xor(z, o);
        zinv = 1.0f / z;
        for (int e = beg; e < end; e += 2) {
            int ee = e + half;
            if (ee < end) {
                int s = col[ee];
                float ev = es[s] + edv;
                ev = ev > 0.f ? ev : 0.2f * ev;
                float alpha = __expf(ev) * zinv;
                ushort4 u = *(const ushort4*)(h16 + (size_t)s * 128 + l32 * 4);
                acc0.x = fmaf(alpha, bf2f(u.x), acc0.x);
                acc0.y = fmaf(alpha, bf2f(u.y), acc0.y);
                acc0.z = fmaf(alpha, bf2f(u.z), acc0.z);
                acc0.w = fmaf(alpha, bf2f(u.w), acc0.w);
            }
        }
    }
    float4 acc = make_float4((acc0.x + acc1.x) + (acc2.x + acc3.x),
                             (acc0.y + acc1.y) + (acc2.y + acc3.y),
                             (acc0.z + acc1.z) + (acc2.z + acc3.z),
                             (acc0.w + acc1.w) + (acc2.w + acc3.w));
    acc.x += __shfl_xor(acc.x, 32);
    acc.y += __shfl_xor(acc.y, 32);
    acc.z += __shfl_xor(acc.z, 32);
    acc.w += __shfl_xor(acc.w, 32);
    if (half == 0) {
        float4 bv = *(const float4*)(b2 + l32 * 4);
        *(float4*)(out + (size_t)n * 128 + l32 * 4) =
            make_float4(acc.x + bv.x, acc.y + bv.y, acc.z + bv.z, acc.w + bv.w);
    }
}

// ===================== launch =====================
extern "C" void kernel_launch(void* const* d_in, const int* in_sizes, int n_in,
                              void* d_out, int out_size, void* d_ws, size_t ws_size,
                              hipStream_t stream) {
    const float* x   = (const float*)d_in[0];
    const int*   ei  = (const int*)d_in[1];
    const float* W1  = (const float*)d_in[2];
    const float* as1 = (const float*)d_in[3];
    const float* ad1 = (const float*)d_in[4];
    const float* b1  = (const float*)d_in[5];
    const float* W2  = (const float*)d_in[6];
    const float* as2 = (const float*)d_in[7];
    const float* ad2 = (const float*)d_in[8];
    const float* b2  = (const float*)d_in[9];
    float* out = (float*)d_out;

    const int N = in_sizes[0] / 128;   // 50000
    const int E = in_sizes[1] / 2;     // 800000
    const int Etot = E + N;
    const int* src = ei;
    const int* dst = ei + E;
    const int NBUCK = (N + 255) / 256;        // 196 buckets of 256 nodes
    const int PB = (Etot + EPB - 1) / EPB;    // fat partition blocks

    // ---- workspace layout (16B-aligned chunks) ----
    char* p = (char*)d_ws;
    unsigned short* X16 = (unsigned short*)p; p += (size_t)N * 128 * 2;
    unsigned short* H2  = (unsigned short*)p; p += (size_t)N * 128 * 2;  // layer2 h
    unsigned short* B16 = (unsigned short*)p; p += (size_t)N * 256 * 2;  // layer1 out
    unsigned short* Wt1 = (unsigned short*)p; p += (size_t)256 * 128 * 2;
    unsigned short* Wt2 = (unsigned short*)p; p += (size_t)128 * 256 * 2;
    float* Q1  = (float*)p;               p += 128 * 8 * 4;
    float* Q2  = (float*)p;               p += 256 * 2 * 4;
    float* es1 = (float*)p;               p += (size_t)N * 4 * 4;
    float* ed1 = (float*)p;               p += (size_t)N * 4 * 4;
    float* es2 = (float*)p;               p += (size_t)N * 4;
    float* ed2 = (float*)p;               p += (size_t)N * 4;
    int* bcnt = (int*)p;                  p += 256 * 4;   // memset to 0
    int* bbase = (int*)p;                 p += 256 * 4;
    int* bcursor = (int*)p;               p += 256 * 4;
    int* ebuf = (int*)p;                  p += (size_t)Etot * 4;
    int* col = (int*)p;                   p += (size_t)Etot * 4;
    int* rowptr = (int*)p;                p += (size_t)(N + 1) * 4;

    // ---- prep (bucket-count first, then conv + Wt + Q) ----
    const int nx4 = N * 128 / 4;
    const int nb_convx = (nx4 + 255) / 256;
    const int nb_prep = PB + nb_convx + 128 + 128 + 32 + 64;
    hipMemsetAsync(bcnt, 0, 256 * sizeof(int), stream);
    prep<<<nb_prep, 256, 0, stream>>>(x, X16, nx4, dst, E, Etot, bcnt,
                                      W1, Wt1, W2, Wt2, as1, ad1, Q1,
                                      as2, ad2, Q2, PB, nb_convx);

    // ---- bucket scan (1 block) ----
    bscan<<<1, 256, 0, stream>>>(bcnt, bbase, bcursor, rowptr, NBUCK, N, Etot);

    // ---- partition + attn1 ----
    const int AB = (N + 3) / 4;
    part_attn1<<<PB + AB, 256, 0, stream>>>(X16, Q1, es1, ed1, N, PB,
                                            src, dst, E, Etot, bcursor, ebuf);

    // ---- per-bucket CSR build (XCD-local writes) ----
    bucket_scatter<<<NBUCK, 256, 0, stream>>>(bbase, bcnt, ebuf, rowptr, col, N);

    // ---- layer 1: fused aggregate + per-head MFMA projection ----
    agg1_fused<<<(N + 15) / 16, 256, 0, stream>>>(rowptr, col, X16, es1, ed1,
                                                  Wt1, b1, B16, N);

    // ---- layer 2: GEMM2 + attn2, then aggregate h2 rows ----
    const int tiles = (N + 15) / 16;
    const int GB2 = (tiles * 2 + 3) / 4;
    gemm_attn2<<<GB2 + AB, 256, 0, stream>>>(B16, Wt2, Q2, H2, es2, ed2, N, GB2);
    agg_l2<<<(N + 3) / 4, 256, 0, stream>>>(rowptr, col, H2, es2, ed2, b2, out, N);
}

// Round 12
// 293.139 us; speedup vs baseline: 1.0991x; 1.0991x over previous
//
#include <hip/hip_runtime.h>
#include <hip/hip_bf16.h>
#include <math.h>

typedef short bf16x8 __attribute__((ext_vector_type(8)));
typedef float f32x4 __attribute__((ext_vector_type(4)));

#define DEG_CAP 128   // per-node LDS logit cache; fallback path beyond
#define EPB 8192      // edges per fat partition block

// ---- bf16 helpers (RN-even down-convert, exact up-convert) ----
__device__ __forceinline__ unsigned short f2bf(float f) {
    unsigned x = __float_as_uint(f);
    unsigned r = x + 0x7FFFu + ((x >> 16) & 1u);
    return (unsigned short)(r >> 16);
}
__device__ __forceinline__ float bf2f(unsigned short u) {
    return __uint_as_float(((unsigned)u) << 16);
}

// ===================== prep: bucket-count + conv_x + Wt + Q =====================
__global__ __launch_bounds__(256) void prep(const float* __restrict__ x,
                                            unsigned short* __restrict__ X16, int nx4,
                                            const int* __restrict__ dst, int E, int Etot,
                                            int* __restrict__ bcnt,
                                            const float* __restrict__ W1,
                                            unsigned short* __restrict__ Wt1,
                                            const float* __restrict__ W2,
                                            unsigned short* __restrict__ Wt2,
                                            const float* __restrict__ as1,
                                            const float* __restrict__ ad1,
                                            float* __restrict__ Q1,
                                            const float* __restrict__ as2,
                                            const float* __restrict__ ad2,
                                            float* __restrict__ Q2,
                                            int nb_bucket, int nb_convx) {
    int b = blockIdx.x, t = threadIdx.x;
    if (b < nb_bucket) {                      // ---- bucket histogram (dst>>8) ----
        __shared__ int h[256];
        h[t] = 0;
        __syncthreads();
        int k0 = b * EPB;
        for (int i = t; i < EPB; i += 256) {
            int k = k0 + i;
            if (k < Etot) {
                int d = k < E ? dst[k] : k - E;
                atomicAdd(&h[d >> 8], 1);
            }
        }
        __syncthreads();
        if (h[t]) atomicAdd(bcnt + t, h[t]);
        return;
    }
    b -= nb_bucket;
    if (b < nb_convx) {                       // ---- x fp32 -> bf16 (float4) ----
        int i = b * 256 + t;
        if (i < nx4) {
            float4 v = ((const float4*)x)[i];
            ushort4 u;
            u.x = f2bf(v.x); u.y = f2bf(v.y); u.z = f2bf(v.z); u.w = f2bf(v.w);
            ((ushort4*)X16)[i] = u;
        }
        return;
    }
    b -= nb_convx;
    if (b < 128) {                            // ---- W1 [128][256] -> Wt1 [256][128]
        int id = b * 256 + t;
        int k = id >> 8, m = id & 255;
        Wt1[m * 128 + k] = f2bf(W1[id]);
        return;
    }
    b -= 128;
    if (b < 128) {                            // ---- W2 [256][128] -> Wt2 [128][256]
        int id = b * 256 + t;
        int k = id >> 7, m = id & 127;
        Wt2[m * 256 + k] = f2bf(W2[id]);
        return;
    }
    b -= 128;
    int wave = t >> 6, lane = t & 63;
    if (b < 32) {                             // ---- Q1 [128][8] ----
        int k = b * 4 + wave;
        if (k < 128) {
            float p[8];
            #pragma unroll
            for (int h = 0; h < 4; ++h) {
                float w = W1[k * 256 + h * 64 + lane];
                p[h] = w * as1[h * 64 + lane];
                p[4 + h] = w * ad1[h * 64 + lane];
            }
            #pragma unroll
            for (int j = 0; j < 8; ++j)
                #pragma unroll
                for (int o = 32; o; o >>= 1) p[j] += __shfl_xor(p[j], o);
            if (lane == 0) {
                #pragma unroll
                for (int j = 0; j < 8; ++j) Q1[k * 8 + j] = p[j];
            }
        }
        return;
    }
    b -= 32;
    {                                         // ---- Q2 [256][2] ----
        int k = b * 4 + wave;
        if (k < 256) {
            float w0 = W2[k * 128 + lane], w1 = W2[k * 128 + 64 + lane];
            float s = w0 * as2[lane] + w1 * as2[64 + lane];
            float d = w0 * ad2[lane] + w1 * ad2[64 + lane];
            #pragma unroll
            for (int o = 32; o; o >>= 1) { s += __shfl_xor(s, o); d += __shfl_xor(d, o); }
            if (lane == 0) { Q2[k * 2] = s; Q2[k * 2 + 1] = d; }
        }
    }
}

// ===================== bucket scan (1 block, <=256 buckets) =====================
__global__ __launch_bounds__(256) void bscan(const int* __restrict__ bcnt,
                                             int* __restrict__ bbase,
                                             int* __restrict__ bcursor,
                                             int* __restrict__ rowptr,
                                             int nbuck, int N, int Etot) {
    __shared__ int s[256];
    int t = threadIdx.x;
    int v = t < nbuck ? bcnt[t] : 0;
    s[t] = v;
    __syncthreads();
    #pragma unroll
    for (int o = 1; o < 256; o <<= 1) {
        int add = t >= o ? s[t - o] : 0;
        __syncthreads();
        s[t] += add;
        __syncthreads();
    }
    int excl = s[t] - v;
    if (t < nbuck) { bbase[t] = excl; bcursor[t] = excl; }
    if (t == 0) rowptr[N] = Etot;
}

// ===================== fused: partition + attn1 (X.Q1) =====================
__global__ __launch_bounds__(256) void part_attn1(const unsigned short* __restrict__ Xb,
                                                  const float* __restrict__ Q,
                                                  float* __restrict__ es,
                                                  float* __restrict__ ed,
                                                  int N, int PB,
                                                  const int* __restrict__ src,
                                                  const int* __restrict__ dst,
                                                  int E, int Etot,
                                                  int* __restrict__ bcursor,
                                                  int* __restrict__ ebuf) {
    int t = threadIdx.x;
    if ((int)blockIdx.x < PB) {
        __shared__ int h[256], gb[256], lc[256];
        h[t] = 0;
        __syncthreads();
        int k0 = (int)blockIdx.x * EPB;
        for (int i = t; i < EPB; i += 256) {
            int k = k0 + i;
            if (k < Etot) {
                int d = k < E ? dst[k] : k - E;
                atomicAdd(&h[d >> 8], 1);
            }
        }
        __syncthreads();
        if (h[t]) gb[t] = atomicAdd(bcursor + t, h[t]);
        lc[t] = 0;
        __syncthreads();
        for (int i = t; i < EPB; i += 256) {
            int k = k0 + i;
            if (k < Etot) {
                int s = k < E ? src[k] : k - E;
                int d = k < E ? dst[k] : k - E;
                int bkt = d >> 8;
                int p = atomicAdd(&lc[bkt], 1);
                ebuf[gb[bkt] + p] = s | ((d & 0xFF) << 16);  // src:16|dlow:8
            }
        }
        return;
    }
    int wave = t >> 6, lane = t & 63;
    int n = ((int)blockIdx.x - PB) * 4 + wave;
    if (n >= N) return;
    ushort2 xv = *(const ushort2*)(Xb + (size_t)n * 128 + lane * 2);
    float x0 = bf2f(xv.x), x1 = bf2f(xv.y);
    const float* q0 = Q + (size_t)(lane * 2) * 8;
    const float* q1 = q0 + 8;
    float p[8];
    #pragma unroll
    for (int j = 0; j < 8; ++j) p[j] = x0 * q0[j] + x1 * q1[j];
    #pragma unroll
    for (int j = 0; j < 8; ++j)
        #pragma unroll
        for (int o = 32; o; o >>= 1) p[j] += __shfl_xor(p[j], o);
    if (lane == 0) {
        #pragma unroll
        for (int h = 0; h < 4; ++h) {
            es[n * 4 + h] = p[h];
            ed[n * 4 + h] = p[4 + h];
        }
    }
}

// ===================== per-bucket CSR build (XCD-local writes) =================
__global__ __launch_bounds__(256) void bucket_scatter(const int* __restrict__ bbase,
                                                      const int* __restrict__ bcnt,
                                                      const int* __restrict__ ebuf,
                                                      int* __restrict__ rowptr,
                                                      int* __restrict__ col, int N) {
    __shared__ int ldeg[256], loff[256], lcur[256];
    int b = blockIdx.x, t = threadIdx.x;
    int base = bbase[b], cnt = bcnt[b];
    ldeg[t] = 0;
    __syncthreads();
    for (int i = t; i < cnt; i += 256) {
        int e = ebuf[base + i];
        atomicAdd(&ldeg[(e >> 16) & 0xFF], 1);
    }
    __syncthreads();
    int v = ldeg[t];
    loff[t] = v;
    __syncthreads();
    #pragma unroll
    for (int o = 1; o < 256; o <<= 1) {
        int add = t >= o ? loff[t - o] : 0;
        __syncthreads();
        loff[t] += add;
        __syncthreads();
    }
    int excl = loff[t] - v;
    __syncthreads();
    loff[t] = excl;
    lcur[t] = 0;
    int node = b * 256 + t;
    if (node < N) rowptr[node] = base + excl;
    __syncthreads();
    for (int i = t; i < cnt; i += 256) {
        int e = ebuf[base + i];
        int dl = (e >> 16) & 0xFF;
        int p = atomicAdd(&lcur[dl], 1);
        col[base + loff[dl] + p] = e & 0xFFFF;
    }
}

// ===================== agg_l1x: no-max softmax + x-row aggregation ==========
// G[n][h*128+k] = sum_e alpha_e^h * x[src_e][k]  (one wave per node)
__global__ __launch_bounds__(256) void agg_l1x(const int* __restrict__ rowptr,
                                               const int* __restrict__ col,
                                               const unsigned short* __restrict__ x16,
                                               const float* __restrict__ es,
                                               const float* __restrict__ ed,
                                               unsigned short* __restrict__ G16,
                                               int N) {
    __shared__ float pl[4][DEG_CAP * 4];
    __shared__ int ic[4][DEG_CAP];
    __shared__ float zs[4][4];
    int wave = threadIdx.x >> 6, lane = threadIdx.x & 63;
    int n = blockIdx.x * 4 + wave;
    if (n >= N) return;
    int h = lane >> 4, l16 = lane & 15;
    int beg = rowptr[n], end = rowptr[n + 1], deg = end - beg;
    float edv = ed[n * 4 + h];
    float* myp = pl[wave];
    int* myc = ic[wave];
    float z = 0.f;
    float a0c0 = 0.f, a0c1 = 0.f, a1c0 = 0.f, a1c1 = 0.f;
    float a2c0 = 0.f, a2c1 = 0.f, a3c0 = 0.f, a3c1 = 0.f;
    float b0c0 = 0.f, b0c1 = 0.f, b1c0 = 0.f, b1c1 = 0.f;
    float b2c0 = 0.f, b2c1 = 0.f, b3c0 = 0.f, b3c1 = 0.f;
    const unsigned short* xbase = x16 + lane * 2;
    if (deg <= DEG_CAP) {
        // merged gather + exp + denom (no-max: logits are O(+-5), fp32 exp safe)
        for (int i = l16; i < deg; i += 16) {
            int s = col[beg + i];
            if (h == 0) myc[i] = s;
            float e = es[s * 4 + h] + edv;
            e = e > 0.f ? e : 0.2f * e;
            float pp = __expf(e);
            myp[i * 4 + h] = pp;
            z += pp;
        }
        #pragma unroll
        for (int o = 8; o; o >>= 1) z += __shfl_xor(z, o);
        if (l16 == 0) zs[wave][h] = 1.0f / z;
        __threadfence_block();
        float4 zi = *(float4*)zs[wave];
        int i = 0;
        for (; i + 2 <= deg; i += 2) {
            float4 p0 = *(float4*)(myp + i * 4);
            float4 p1 = *(float4*)(myp + i * 4 + 4);
            int s0 = myc[i], s1 = myc[i + 1];
            ushort2 u0 = *(const ushort2*)(xbase + (size_t)s0 * 128);
            ushort2 u1 = *(const ushort2*)(xbase + (size_t)s1 * 128);
            float x00 = bf2f(u0.x), x01 = bf2f(u0.y);
            float x10 = bf2f(u1.x), x11 = bf2f(u1.y);
            float al0 = p0.x * zi.x, al1 = p0.y * zi.y;
            float al2 = p0.z * zi.z, al3 = p0.w * zi.w;
            float bl0 = p1.x * zi.x, bl1 = p1.y * zi.y;
            float bl2 = p1.z * zi.z, bl3 = p1.w * zi.w;
            a0c0 = fmaf(al0, x00, a0c0); a0c1 = fmaf(al0, x01, a0c1);
            a1c0 = fmaf(al1, x00, a1c0); a1c1 = fmaf(al1, x01, a1c1);
            a2c0 = fmaf(al2, x00, a2c0); a2c1 = fmaf(al2, x01, a2c1);
            a3c0 = fmaf(al3, x00, a3c0); a3c1 = fmaf(al3, x01, a3c1);
            b0c0 = fmaf(bl0, x10, b0c0); b0c1 = fmaf(bl0, x11, b0c1);
            b1c0 = fmaf(bl1, x10, b1c0); b1c1 = fmaf(bl1, x11, b1c1);
            b2c0 = fmaf(bl2, x10, b2c0); b2c1 = fmaf(bl2, x11, b2c1);
            b3c0 = fmaf(bl3, x10, b3c0); b3c1 = fmaf(bl3, x11, b3c1);
        }
        if (i < deg) {
            float4 p0 = *(float4*)(myp + i * 4);
            int s0 = myc[i];
            ushort2 u0 = *(const ushort2*)(xbase + (size_t)s0 * 128);
            float x00 = bf2f(u0.x), x01 = bf2f(u0.y);
            float al0 = p0.x * zi.x, al1 = p0.y * zi.y;
            float al2 = p0.z * zi.z, al3 = p0.w * zi.w;
            a0c0 = fmaf(al0, x00, a0c0); a0c1 = fmaf(al0, x01, a0c1);
            a1c0 = fmaf(al1, x00, a1c0); a1c1 = fmaf(al1, x01, a1c1);
            a2c0 = fmaf(al2, x00, a2c0); a2c1 = fmaf(al2, x01, a2c1);
            a3c0 = fmaf(al3, x00, a3c0); a3c1 = fmaf(al3, x01, a3c1);
        }
    } else {
        // fallback: recompute per edge (deg > DEG_CAP, rare)
        float z2 = 0.f;
        for (int e = beg + l16; e < end; e += 16) {
            float ev = es[col[e] * 4 + h] + edv;
            ev = ev > 0.f ? ev : 0.2f * ev;
            z2 += __expf(ev);
        }
        #pragma unroll
        for (int o = 8; o; o >>= 1) z2 += __shfl_xor(z2, o);
        if (l16 == 0) zs[wave][h] = 1.0f / z2;
        __threadfence_block();
        float4 zi = *(float4*)zs[wave];
        float4 ed4 = *(const float4*)(ed + n * 4);
        for (int e = beg; e < end; ++e) {
            int s = col[e];
            float4 es4 = *(const float4*)(es + s * 4);
            float e0 = es4.x + ed4.x; e0 = e0 > 0.f ? e0 : 0.2f * e0;
            float e1 = es4.y + ed4.y; e1 = e1 > 0.f ? e1 : 0.2f * e1;
            float e2 = es4.z + ed4.z; e2 = e2 > 0.f ? e2 : 0.2f * e2;
            float e3 = es4.w + ed4.w; e3 = e3 > 0.f ? e3 : 0.2f * e3;
            float al0 = __expf(e0) * zi.x;
            float al1 = __expf(e1) * zi.y;
            float al2 = __expf(e2) * zi.z;
            float al3 = __expf(e3) * zi.w;
            ushort2 u0 = *(const ushort2*)(xbase + (size_t)s * 128);
            float x00 = bf2f(u0.x), x01 = bf2f(u0.y);
            a0c0 = fmaf(al0, x00, a0c0); a0c1 = fmaf(al0, x01, a0c1);
            a1c0 = fmaf(al1, x00, a1c0); a1c1 = fmaf(al1, x01, a1c1);
            a2c0 = fmaf(al2, x00, a2c0); a2c1 = fmaf(al2, x01, a2c1);
            a3c0 = fmaf(al3, x00, a3c0); a3c1 = fmaf(al3, x01, a3c1);
        }
    }
    unsigned short* g = G16 + (size_t)n * 512 + lane * 2;
    ushort2 o0 = {f2bf(a0c0 + b0c0), f2bf(a0c1 + b0c1)};
    ushort2 o1 = {f2bf(a1c0 + b1c0), f2bf(a1c1 + b1c1)};
    ushort2 o2 = {f2bf(a2c0 + b2c0), f2bf(a2c1 + b2c1)};
    ushort2 o3 = {f2bf(a3c0 + b3c0), f2bf(a3c1 + b3c1)};
    *(ushort2*)(g + 0)   = o0;
    *(ushort2*)(g + 128) = o1;
    *(ushort2*)(g + 256) = o2;
    *(ushort2*)(g + 384) = o3;
}

// ===================== proj2: h1 proj (LDS) + GEMM2 + attn2 fused ===========
// Block = 16 nodes. Phase A (wave=head): h1 = ELU(G@W1_h + b1) -> LDS tile.
// Phase B: GEMM2 from LDS (wave = 32-col slab) + es2/ed2 dots from LDS.
__global__ __launch_bounds__(256) void proj2(const unsigned short* __restrict__ G16,
                                             const unsigned short* __restrict__ Wt1,
                                             const float* __restrict__ b1,
                                             const unsigned short* __restrict__ Wt2,
                                             const float* __restrict__ Q2,
                                             unsigned short* __restrict__ H2,
                                             float* __restrict__ es,
                                             float* __restrict__ ed, int N) {
    __shared__ unsigned short Hlds[16][264];  // +8 pad; rows 16B-aligned (528B)
    int wave = threadIdx.x >> 6, lane = threadIdx.x & 63;
    int l15 = lane & 15, quad = lane >> 4;
    int m0 = blockIdx.x * 16;
    // ---- phase A: per-head projection into LDS ----
    {
        int h = wave;
        int ar = m0 + l15; if (ar >= N) ar = N - 1;
        f32x4 acc[4] = {};
        const unsigned short* arow = G16 + (size_t)ar * 512 + h * 128 + quad * 8;
        const unsigned short* brow = Wt1 + (size_t)(h * 64 + l15) * 128 + quad * 8;
        #pragma unroll
        for (int k0 = 0; k0 < 128; k0 += 32) {
            bf16x8 a = *(const bf16x8*)(arow + k0);
            #pragma unroll
            for (int nt = 0; nt < 4; ++nt) {
                bf16x8 b = *(const bf16x8*)(brow + (size_t)nt * 16 * 128 + k0);
                acc[nt] = __builtin_amdgcn_mfma_f32_16x16x32_bf16(a, b, acc[nt], 0, 0, 0);
            }
        }
        #pragma unroll
        for (int nt = 0; nt < 4; ++nt) {
            float bias = b1[h * 64 + nt * 16 + l15];
            #pragma unroll
            for (int r = 0; r < 4; ++r) {
                float v = acc[nt][r] + bias;
                v = v > 0.f ? v : expm1f(v);
                Hlds[quad * 4 + r][h * 64 + nt * 16 + l15] = f2bf(v);
            }
        }
    }
    __syncthreads();
    // ---- phase B1: GEMM2 (16x128 out, K=256); wave covers cols wave*32.. ----
    {
        f32x4 acc2[2] = {};
        #pragma unroll
        for (int k0 = 0; k0 < 256; k0 += 32) {
            bf16x8 a = *(const bf16x8*)(&Hlds[l15][quad * 8 + k0]);
            #pragma unroll
            for (int j = 0; j < 2; ++j) {
                const unsigned short* b =
                    Wt2 + (size_t)(wave * 32 + j * 16 + l15) * 256 + quad * 8 + k0;
                acc2[j] = __builtin_amdgcn_mfma_f32_16x16x32_bf16(
                    a, *(const bf16x8*)b, acc2[j], 0, 0, 0);
            }
        }
        #pragma unroll
        for (int j = 0; j < 2; ++j)
            #pragma unroll
            for (int r = 0; r < 4; ++r) {
                int row = m0 + quad * 4 + r;
                if (row < N)
                    H2[(size_t)row * 128 + wave * 32 + j * 16 + l15] =
                        f2bf(acc2[j][r]);
            }
    }
    // ---- phase B2: attn2 dots for 4 nodes per wave ----
    for (int j = 0; j < 4; ++j) {
        int lr = wave * 4 + j;
        int n = m0 + lr;
        if (n >= N) break;
        ushort4 hv = *(const ushort4*)(&Hlds[lr][lane * 4]);
        float xr[4] = {bf2f(hv.x), bf2f(hv.y), bf2f(hv.z), bf2f(hv.w)};
        float p0 = 0.f, p1 = 0.f;
        #pragma unroll
        for (int tt = 0; tt < 4; ++tt) {
            float2 q = *(const float2*)(Q2 + (size_t)(lane * 4 + tt) * 2);
            p0 = fmaf(xr[tt], q.x, p0);
            p1 = fmaf(xr[tt], q.y, p1);
        }
        #pragma unroll
        for (int o = 32; o; o >>= 1) { p0 += __shfl_xor(p0, o); p1 += __shfl_xor(p1, o); }
        if (lane == 0) { es[n] = p0; ed[n] = p1; }
    }
}

// ===================== agg_l2 (no-max softmax; gather h2 rows 256B) =========
__global__ __launch_bounds__(256) void agg_l2(const int* __restrict__ rowptr,
                                              const int* __restrict__ col,
                                              const unsigned short* __restrict__ h16,
                                              const float* __restrict__ es,
                                              const float* __restrict__ ed,
                                              const float* __restrict__ b2,
                                              float* __restrict__ out, int N) {
    __shared__ float pl[4][DEG_CAP];
    __shared__ int ic[4][DEG_CAP];
    int wave = threadIdx.x >> 6, lane = threadIdx.x & 63;
    int n = blockIdx.x * 4 + wave;
    if (n >= N) return;
    int beg = rowptr[n], end = rowptr[n + 1], deg = end - beg;
    float edv = ed[n];
    float* myp = pl[wave];
    int* myc = ic[wave];
    float z = 0.f, zinv;
    int half = lane >> 5, l32 = lane & 31;
    float4 acc0 = make_float4(0.f, 0.f, 0.f, 0.f);
    float4 acc1 = make_float4(0.f, 0.f, 0.f, 0.f);
    float4 acc2 = make_float4(0.f, 0.f, 0.f, 0.f);
    float4 acc3 = make_float4(0.f, 0.f, 0.f, 0.f);
    if (deg <= DEG_CAP) {
        for (int i = lane; i < deg; i += 64) {
            int s = col[beg + i];
            myc[i] = s;
            float e = es[s] + edv;
            e = e > 0.f ? e : 0.2f * e;
            float pp = __expf(e);
            myp[i] = pp;
            z += pp;
        }
        #pragma unroll
        for (int o = 32; o; o >>= 1) z += __shfl_xor(z, o);
        zinv = 1.0f / z;
        __threadfence_block();
        int i = 0;
        for (; i + 8 <= deg; i += 8) {
            int ii0 = i + half, ii1 = i + 2 + half, ii2 = i + 4 + half, ii3 = i + 6 + half;
            float a0 = myp[ii0] * zinv, a1 = myp[ii1] * zinv;
            float a2 = myp[ii2] * zinv, a3 = myp[ii3] * zinv;
            ushort4 u0 = *(const ushort4*)(h16 + (size_t)myc[ii0] * 128 + l32 * 4);
            ushort4 u1 = *(const ushort4*)(h16 + (size_t)myc[ii1] * 128 + l32 * 4);
            ushort4 u2 = *(const ushort4*)(h16 + (size_t)myc[ii2] * 128 + l32 * 4);
            ushort4 u3 = *(const ushort4*)(h16 + (size_t)myc[ii3] * 128 + l32 * 4);
            acc0.x = fmaf(a0, bf2f(u0.x), acc0.x);
            acc0.y = fmaf(a0, bf2f(u0.y), acc0.y);
            acc0.z = fmaf(a0, bf2f(u0.z), acc0.z);
            acc0.w = fmaf(a0, bf2f(u0.w), acc0.w);
            acc1.x = fmaf(a1, bf2f(u1.x), acc1.x);
            acc1.y = fmaf(a1, bf2f(u1.y), acc1.y);
            acc1.z = fmaf(a1, bf2f(u1.z), acc1.z);
            acc1.w = fmaf(a1, bf2f(u1.w), acc1.w);
            acc2.x = fmaf(a2, bf2f(u2.x), acc2.x);
            acc2.y = fmaf(a2, bf2f(u2.y), acc2.y);
            acc2.z = fmaf(a2, bf2f(u2.z), acc2.z);
            acc2.w = fmaf(a2, bf2f(u2.w), acc2.w);
            acc3.x = fmaf(a3, bf2f(u3.x), acc3.x);
            acc3.y = fmaf(a3, bf2f(u3.y), acc3.y);
            acc3.z = fmaf(a3, bf2f(u3.z), acc3.z);
            acc3.w = fmaf(a3, bf2f(u3.w), acc3.w);
        }
        for (; i < deg; i += 2) {
            int ii = i + half;
            if (ii < deg) {
                float a0 = myp[ii] * zinv;
                ushort4 u0 = *(const ushort4*)(h16 + (size_t)myc[ii] * 128 + l32 * 4);
                acc0.x = fmaf(a0, bf2f(u0.x), acc0.x);
                acc0.y = fmaf(a0, bf2f(u0.y), acc0.y);
                acc0.z = fmaf(a0, bf2f(u0.z), acc0.z);
                acc0.w = fmaf(a0, bf2f(u0.w), acc0.w);
            }
        }
    } else {
        for (int e = beg + lane; e < end; e += 64) {
            float ev = es[col[e]] + edv;
            ev = ev > 0.f ? ev : 0.2f * ev;
            z += __expf(ev);
        }
        #pragma unroll
        for (int o = 32; o; o >>= 1) z += __shfl_xor(z, o);
        zinv = 1.0f / z;
        for (int e = beg; e < end; e += 2) {
            int ee = e + half;
            if (ee < end) {
                int s = col[ee];
                float ev = es[s] + edv;
                ev = ev > 0.f ? ev : 0.2f * ev;
                float alpha = __expf(ev) * zinv;
                ushort4 u = *(const ushort4*)(h16 + (size_t)s * 128 + l32 * 4);
                acc0.x = fmaf(alpha, bf2f(u.x), acc0.x);
                acc0.y = fmaf(alpha, bf2f(u.y), acc0.y);
                acc0.z = fmaf(alpha, bf2f(u.z), acc0.z);
                acc0.w = fmaf(alpha, bf2f(u.w), acc0.w);
            }
        }
    }
    float4 acc = make_float4((acc0.x + acc1.x) + (acc2.x + acc3.x),
                             (acc0.y + acc1.y) + (acc2.y + acc3.y),
                             (acc0.z + acc1.z) + (acc2.z + acc3.z),
                             (acc0.w + acc1.w) + (acc2.w + acc3.w));
    acc.x += __shfl_xor(acc.x, 32);
    acc.y += __shfl_xor(acc.y, 32);
    acc.z += __shfl_xor(acc.z, 32);
    acc.w += __shfl_xor(acc.w, 32);
    if (half == 0) {
        float4 bv = *(const float4*)(b2 + l32 * 4);
        *(float4*)(out + (size_t)n * 128 + l32 * 4) =
            make_float4(acc.x + bv.x, acc.y + bv.y, acc.z + bv.z, acc.w + bv.w);
    }
}

// ===================== launch =====================
extern "C" void kernel_launch(void* const* d_in, const int* in_sizes, int n_in,
                              void* d_out, int out_size, void* d_ws, size_t ws_size,
                              hipStream_t stream) {
    const float* x   = (const float*)d_in[0];
    const int*   ei  = (const int*)d_in[1];
    const float* W1  = (const float*)d_in[2];
    const float* as1 = (const float*)d_in[3];
    const float* ad1 = (const float*)d_in[4];
    const float* b1  = (const float*)d_in[5];
    const float* W2  = (const float*)d_in[6];
    const float* as2 = (const float*)d_in[7];
    const float* ad2 = (const float*)d_in[8];
    const float* b2  = (const float*)d_in[9];
    float* out = (float*)d_out;

    const int N = in_sizes[0] / 128;   // 50000
    const int E = in_sizes[1] / 2;     // 800000
    const int Etot = E + N;
    const int* src = ei;
    const int* dst = ei + E;
    const int NBUCK = (N + 255) / 256;        // 196 buckets of 256 nodes
    const int PB = (Etot + EPB - 1) / EPB;    // fat partition blocks

    // ---- workspace layout (16B-aligned chunks) ----
    char* p = (char*)d_ws;
    unsigned short* X16 = (unsigned short*)p; p += (size_t)N * 128 * 2;
    unsigned short* H2  = (unsigned short*)p; p += (size_t)N * 128 * 2;
    unsigned short* G16 = (unsigned short*)p; p += (size_t)N * 512 * 2;
    unsigned short* Wt1 = (unsigned short*)p; p += (size_t)256 * 128 * 2;
    unsigned short* Wt2 = (unsigned short*)p; p += (size_t)128 * 256 * 2;
    float* Q1  = (float*)p;               p += 128 * 8 * 4;
    float* Q2  = (float*)p;               p += 256 * 2 * 4;
    float* es1 = (float*)p;               p += (size_t)N * 4 * 4;
    float* ed1 = (float*)p;               p += (size_t)N * 4 * 4;
    float* es2 = (float*)p;               p += (size_t)N * 4;
    float* ed2 = (float*)p;               p += (size_t)N * 4;
    int* bcnt = (int*)p;                  p += 256 * 4;   // memset to 0
    int* bbase = (int*)p;                 p += 256 * 4;
    int* bcursor = (int*)p;               p += 256 * 4;
    int* ebuf = (int*)p;                  p += (size_t)Etot * 4;
    int* col = (int*)p;                   p += (size_t)Etot * 4;
    int* rowptr = (int*)p;                p += (size_t)(N + 1) * 4;

    // ---- prep (bucket-count first, then conv + Wt + Q) ----
    const int nx4 = N * 128 / 4;
    const int nb_convx = (nx4 + 255) / 256;
    const int nb_prep = PB + nb_convx + 128 + 128 + 32 + 64;
    hipMemsetAsync(bcnt, 0, 256 * sizeof(int), stream);
    prep<<<nb_prep, 256, 0, stream>>>(x, X16, nx4, dst, E, Etot, bcnt,
                                      W1, Wt1, W2, Wt2, as1, ad1, Q1,
                                      as2, ad2, Q2, PB, nb_convx);

    // ---- bucket scan (1 block) ----
    bscan<<<1, 256, 0, stream>>>(bcnt, bbase, bcursor, rowptr, NBUCK, N, Etot);

    // ---- partition + attn1 ----
    const int AB = (N + 3) / 4;
    part_attn1<<<PB + AB, 256, 0, stream>>>(X16, Q1, es1, ed1, N, PB,
                                            src, dst, E, Etot, bcursor, ebuf);

    // ---- per-bucket CSR build (XCD-local writes) ----
    bucket_scatter<<<NBUCK, 256, 0, stream>>>(bbase, bcnt, ebuf, rowptr, col, N);

    // ---- layer 1 aggregation (wave per node, best measured config) ----
    agg_l1x<<<(N + 3) / 4, 256, 0, stream>>>(rowptr, col, X16, es1, ed1, G16, N);

    // ---- fused: h1 projection + GEMM2 + attn2 (B16 never hits global) ----
    const int tiles = (N + 15) / 16;
    proj2<<<tiles, 256, 0, stream>>>(G16, Wt1, b1, Wt2, Q2, H2, es2, ed2, N);

    // ---- layer 2 aggregation ----
    agg_l2<<<(N + 3) / 4, 256, 0, stream>>>(rowptr, col, H2, es2, ed2, b2, out, N);
}